// Round 3
// baseline (546.773 us; speedup 1.0000x reference)
//
#include <hip/hip_runtime.h>

// BFP quantization: blocks of 16 consecutive floats along last dim share one
// exponent (floor(log2(max|x|))), 8-bit signed mantissa (qmin=-128, qmax=127).
//
// R3: same structure as R2 (one thread per 16-elem block, 4x dwordx4 MLP,
// no cross-lane ops) but with native ext_vector_type float4 so the
// nontemporal store builtin accepts the pointer (HIP_vector_type is a
// struct and was rejected at compile time in R2).

typedef float vfloat4 __attribute__((ext_vector_type(4)));

__global__ __launch_bounds__(256) void bfp_quant_kernel(
    const vfloat4* __restrict__ x, vfloat4* __restrict__ out, int nblk) {
    int b = blockIdx.x * blockDim.x + threadIdx.x;
    if (b >= nblk) return;

    const vfloat4* px = x + (size_t)b * 4;
    vfloat4 v0 = px[0];
    vfloat4 v1 = px[1];
    vfloat4 v2 = px[2];
    vfloat4 v3 = px[3];

    // max |.| over the 16 elements (abs folds into v_max3 input modifiers)
    float m0 = fmaxf(fmaxf(fabsf(v0.x), fabsf(v0.y)), fmaxf(fabsf(v0.z), fabsf(v0.w)));
    float m1 = fmaxf(fmaxf(fabsf(v1.x), fabsf(v1.y)), fmaxf(fabsf(v1.z), fabsf(v1.w)));
    float m2 = fmaxf(fmaxf(fabsf(v2.x), fabsf(v2.y)), fmaxf(fabsf(v2.z), fabsf(v2.w)));
    float m3 = fmaxf(fmaxf(fabsf(v3.x), fabsf(v3.y)), fmaxf(fabsf(v3.z), fabsf(v3.w)));
    float m = fmaxf(fmaxf(m0, m1), fmaxf(m2, m3));

    // safe_max guard identical to reference: zero block -> scale from 1.0,
    // all values 0 so output is exactly 0 (no inf/NaN path).
    float sm = (m > 0.0f) ? m : 1.0f;

    // floor(log2(sm)) for normal floats = unbiased exponent field
    int e = (int)(__float_as_uint(sm) >> 23) - 127;

    float scale = __builtin_amdgcn_ldexpf(1.0f, e - 7);  // 2^(e-(mbits-1))
    float inv   = __builtin_amdgcn_ldexpf(1.0f, 7 - e);  // exact reciprocal

#define QQ(t) (fminf(fmaxf(rintf((t) * inv), -128.0f), 127.0f) * scale)
    vfloat4 q0 = {QQ(v0.x), QQ(v0.y), QQ(v0.z), QQ(v0.w)};
    vfloat4 q1 = {QQ(v1.x), QQ(v1.y), QQ(v1.z), QQ(v1.w)};
    vfloat4 q2 = {QQ(v2.x), QQ(v2.y), QQ(v2.z), QQ(v2.w)};
    vfloat4 q3 = {QQ(v3.x), QQ(v3.y), QQ(v3.z), QQ(v3.w)};
#undef QQ

    vfloat4* po = out + (size_t)b * 4;
    __builtin_nontemporal_store(q0, po + 0);
    __builtin_nontemporal_store(q1, po + 1);
    __builtin_nontemporal_store(q2, po + 2);
    __builtin_nontemporal_store(q3, po + 3);
}

extern "C" void kernel_launch(void* const* d_in, const int* in_sizes, int n_in,
                              void* d_out, int out_size, void* d_ws, size_t ws_size,
                              hipStream_t stream) {
    const float* x = (const float*)d_in[0];
    float* out = (float*)d_out;
    int n = in_sizes[0];          // 4*4096*4096 = 67108864, divisible by 16
    int nblk = n >> 4;            // 4,194,304 BFP blocks

    const int threads = 256;
    int blocks = (nblk + threads - 1) / threads;   // 16384
    bfp_quant_kernel<<<blocks, threads, 0, stream>>>(
        (const vfloat4*)x, (vfloat4*)out, nblk);
}